// Round 19
// baseline (388.456 us; speedup 1.0000x reference)
//
#include <hip/hip_runtime.h>

#define N_USERS 100000
#define M_ITEMS 50000
#define NNODES  (N_USERS + M_ITEMS)
#define EMBED   64
#define BATCH   8192

#define NU_E ((size_t)N_USERS * EMBED)
#define NE   ((size_t)NNODES * EMBED)    // 9,600,000 elements

#define NPB    256                        // nodes per CSR bucket
#define NBUCK  ((NNODES + NPB - 1) / NPB) // 586
#define PBLK   512                        // partition blocks (1 LDS pass each)
#define PTILE  4688                       // edges per block (512*4688 >= nnz)
#define HBB_N  (NBUCK * PBLK)             // 300,032
#define SCHUNK 2048                       // scan elems per block (256 thr x 8)
#define SNB    ((HBB_N + SCHUNK - 1) / SCHUNK) // 147
#define BCAP   6784                       // LDS capacity per bucket sort
#define PRED_BLOCKS ((BATCH * 64) / 256)  // 2048

typedef unsigned int uint;
typedef uint uint4v __attribute__((ext_vector_type(4)));   // clang vector (nontemporal-ok)

static __device__ __forceinline__ ushort f2bf(float f) {
    uint u = __float_as_uint(f);
    return (ushort)((u + 0x7fffu + ((u >> 16) & 1u)) >> 16);
}
static __device__ __forceinline__ float bf_lo(uint u) { return __uint_as_float(u << 16); }
static __device__ __forceinline__ float bf_hi(uint u) { return __uint_as_float(u & 0xffff0000u); }
static __device__ __forceinline__ float bfs(ushort u) { return __uint_as_float((uint)u << 16); }

// ---------------------------------------------------------------------------
// Fused: blocks [0,PBLK)  = per-block bucket hist -> Hbb[bucket*PBLK+blk]
//        blocks [PBLK,..) = E0 = bf16(concat(eu0, ei0)).
// ---------------------------------------------------------------------------
__global__ void init_and_hist(const float* __restrict__ eu, const float* __restrict__ ei,
                              ushort* __restrict__ E0,
                              const int* __restrict__ src, int* __restrict__ Hbb,
                              int nnz) {
    __shared__ int h[NBUCK];
    if (blockIdx.x < PBLK) {
        for (int i = threadIdx.x; i < NBUCK; i += 1024) h[i] = 0;
        __syncthreads();
        int base = blockIdx.x * PTILE;
        int end  = min(base + PTILE, nnz);
        for (int i = base + threadIdx.x; i < end; i += 1024)
            atomicAdd(&h[src[i] >> 8], 1);
        __syncthreads();
        for (int i = threadIdx.x; i < NBUCK; i += 1024)
            Hbb[i * PBLK + blockIdx.x] = h[i];
    } else {
        size_t t = (size_t)(blockIdx.x - PBLK) * 1024 + threadIdx.x;
        const size_t nu4 = NU_E / 4;
        const size_t n4  = NE / 4;
        if (t >= n4) return;
        float4 v = (t < nu4) ? ((const float4*)eu)[t] : ((const float4*)ei)[t - nu4];
        ((ushort4*)E0)[t] = make_ushort4(f2bf(v.x), f2bf(v.y), f2bf(v.z), f2bf(v.w));
    }
}

// ---------------------------------------------------------------------------
// Scan phase A: block-local exclusive scan of 2048 elems (256 thr x 8)
// ---------------------------------------------------------------------------
__global__ void scan_local(int* __restrict__ h, int* __restrict__ bsum, int n) {
    __shared__ int lds[256];
    const int tid = threadIdx.x;
    const int base = blockIdx.x * SCHUNK + tid * 8;
    int v[8]; int s = 0;
    #pragma unroll
    for (int c = 0; c < 8; ++c) { v[c] = (base + c < n) ? h[base + c] : 0; s += v[c]; }
    lds[tid] = s;
    __syncthreads();
    for (int off = 1; off < 256; off <<= 1) {
        int t = (tid >= off) ? lds[tid - off] : 0;
        __syncthreads();
        lds[tid] += t;
        __syncthreads();
    }
    if (tid == 255) bsum[blockIdx.x] = lds[255];
    int run = (tid > 0) ? lds[tid - 1] : 0;
    #pragma unroll
    for (int c = 0; c < 8; ++c) {
        int t = v[c];
        if (base + c < n) h[base + c] = run;
        run += t;
    }
}

// ---------------------------------------------------------------------------
// Scan phase B+C fused: re-scan bsum in LDS, add block prefix.
// ---------------------------------------------------------------------------
__global__ void scan_add2(int* __restrict__ h, const int* __restrict__ bsum,
                          int n, int nblk) {
    __shared__ int lds[256];
    int tid = threadIdx.x;
    if (tid < 256) lds[tid] = (tid < nblk) ? bsum[tid] : 0;
    __syncthreads();
    for (int off = 1; off < 256; off <<= 1) {
        int t = (tid >= off && tid < 256) ? lds[tid - off] : 0;
        __syncthreads();
        if (tid < 256) lds[tid] += t;
        __syncthreads();
    }
    int prefix = (blockIdx.x > 0) ? lds[blockIdx.x - 1] : 0;
    int lim = min(blockIdx.x * SCHUNK + SCHUNK, n);
    for (int i = blockIdx.x * SCHUNK + tid; i < lim; i += 1024)
        h[i] += prefix;
}

// ---------------------------------------------------------------------------
// Partition: single LDS pass per block (PTILE edges), counting sort in LDS,
// contiguous run write-out using Hbb global cursors.
// ebuf.x = (src & 255) | (dst_local << 8)
// ---------------------------------------------------------------------------
__global__ void __launch_bounds__(1024)
partition2(const int* __restrict__ src, const int* __restrict__ dst,
           const float* __restrict__ vals, const int* __restrict__ Hbb,
           int2* __restrict__ ebuf, int nnz) {
    __shared__ int2 data[PTILE];      // 37.5 KB
    __shared__ int  cnt[NBUCK];
    __shared__ int  cur[NBUCK];
    __shared__ int  s[1024];
    const int blk = blockIdx.x;
    const int tid = threadIdx.x;
    const int base = blk * PTILE;
    const int end  = min(base + PTILE, nnz);

    for (int i = tid; i < NBUCK; i += 1024) cnt[i] = 0;
    __syncthreads();
    for (int i = base + tid; i < end; i += 1024)
        atomicAdd(&cnt[src[i] >> 8], 1);
    __syncthreads();
    s[tid] = (tid < NBUCK) ? cnt[tid] : 0;
    __syncthreads();
    for (int off = 1; off < 1024; off <<= 1) {
        int t = (tid >= off) ? s[tid - off] : 0;
        __syncthreads();
        s[tid] += t;
        __syncthreads();
    }
    if (tid < NBUCK) cur[tid] = (tid > 0) ? s[tid - 1] : 0;
    __syncthreads();
    for (int i = base + tid; i < end; i += 1024) {
        int sv = src[i];
        int d  = dst[i];
        float v = vals[i];
        if (d >= N_USERS) d -= N_USERS;          // bipartite-local dst index
        int p = atomicAdd(&cur[sv >> 8], 1);
        data[p] = make_int2((sv & 255) | (d << 8), __float_as_int(v));
    }
    __syncthreads();
    int grp = tid >> 4, lane16 = tid & 15;        // 64 groups of 16
    for (int b = grp; b < NBUCK; b += 64) {
        int lbeg = (b > 0) ? s[b - 1] : 0;
        int c  = cnt[b];
        int gb = Hbb[b * PBLK + blk];
        for (int j = lane16; j < c; j += 16)
            ebuf[gb + j] = data[lbeg + j];
    }
}

// ---------------------------------------------------------------------------
// One block per bucket: LDS node counts + scan -> offs[], LDS-staged node
// sort -> fully contiguous ep write, + ascending-degree perm.
// ---------------------------------------------------------------------------
__global__ void __launch_bounds__(1024)
bucket_sort_perm(const int* __restrict__ Hbb, const int2* __restrict__ ebuf,
                 int* __restrict__ offs, int2* __restrict__ ep,
                 int* __restrict__ perm, int nnz) {
    __shared__ int2 data[BCAP];       // 54.3 KB
    __shared__ int cnt[256], sc[256], cur[256], dsc[256];
    int b   = blockIdx.x;
    int tid = threadIdx.x;
    int beg = Hbb[b * PBLK];
    int end = (b + 1 < NBUCK) ? Hbb[(b + 1) * PBLK] : nnz;
    int blen = end - beg;
    if (tid < 256) cnt[tid] = 0;
    __syncthreads();
    for (int i = beg + tid; i < end; i += 1024)
        atomicAdd(&cnt[ebuf[i].x & 255], 1);
    __syncthreads();
    if (tid < 256) sc[tid] = cnt[tid];
    __syncthreads();
    for (int off = 1; off < 256; off <<= 1) {
        int t = (tid >= off && tid < 256) ? sc[tid - off] : 0;
        __syncthreads();
        if (tid < 256) sc[tid] += t;
        __syncthreads();
    }
    if (tid < 256) {
        int lbase = (tid > 0) ? sc[tid - 1] : 0;
        int node = b * NPB + tid;
        if (node < NNODES) offs[node] = beg + lbase;
        cur[tid] = lbase;                          // local cursor
    }
    __syncthreads();
    if (blen <= BCAP) {
        for (int i = beg + tid; i < end; i += 1024) {
            int2 e = ebuf[i];
            int p = atomicAdd(&cur[e.x & 255], 1);
            data[p] = make_int2(e.x >> 8, e.y);
        }
        __syncthreads();
        for (int i = tid; i < blen; i += 1024)
            ep[beg + i] = data[i];
    } else {
        for (int i = beg + tid; i < end; i += 1024) {
            int2 e = ebuf[i];
            int p = atomicAdd(&cur[e.x & 255], 1);
            ep[beg + p] = make_int2(e.x >> 8, e.y);
        }
    }
    // ---- perm: counting sort by ASCENDING degree ----
    __syncthreads();
    if (tid < 256) sc[tid] = 0;
    __syncthreads();
    int nodeCount = min(NNODES - b * NPB, NPB);
    int bin = 0;
    if (tid < nodeCount) {
        bin = min(cnt[tid], 255);
        atomicAdd(&sc[bin], 1);
    }
    __syncthreads();
    if (tid < 256) dsc[tid] = sc[tid];
    __syncthreads();
    for (int off = 1; off < 256; off <<= 1) {
        int t = (tid >= off && tid < 256) ? dsc[tid - off] : 0;
        __syncthreads();
        if (tid < 256) dsc[tid] += t;
        __syncthreads();
    }
    if (tid < 256) cur[tid] = b * NPB + ((tid > 0) ? dsc[tid - 1] : 0);
    __syncthreads();
    if (tid < nodeCount) {
        int rank = atomicAdd(&cur[bin], 1);
        perm[rank] = b * NPB + tid;
    }
    if (b == 0 && tid == 0) offs[NNODES] = nnz;
}

// ---------------------------------------------------------------------------
// Gather layer: Enext[node] = sum val * Eprev[dst]
// 8 nodes/wave (degree-sorted), 8 lanes/node, branch-free unroll-8.
// ep loads + Enext store are NONTEMPORAL (streamed, zero reuse) so L2
// retains the reused Eprev rows instead. (Scalar/clang-vector types only.)
// ---------------------------------------------------------------------------
__global__ void gather_E(const int* __restrict__ offs, const int2* __restrict__ ep,
                         const int* __restrict__ perm,
                         const ushort* __restrict__ Eprev, ushort* __restrict__ Enext,
                         int nnz) {
    int t = blockIdx.x * blockDim.x + threadIdx.x;
    int wave = t >> 6;
    int lane = t & 63;
    int g = lane >> 3;
    int q = lane & 7;
    int ln = wave * 8 + g;
    bool valid = ln < NNODES;
    int node = valid ? perm[ln] : 0;
    int start = valid ? offs[node] : 0;
    int deg   = valid ? offs[node + 1] - start : 0;
    bool isUser = node < N_USERS;
    const uint4* other = (const uint4*)(Eprev + (isUser ? NU_E : 0));
    const long long* epq = (const long long*)ep;   // 8B scalar view for nontemporal
    int lastIdx = min(max(start + deg - 1, 0), nnz - 1);

    int md = deg;
    #pragma unroll
    for (int off = 8; off <= 32; off <<= 1) md = max(md, __shfl_xor(md, off));

    float a0=0.f,a1=0.f,a2=0.f,a3=0.f,a4=0.f,a5=0.f,a6=0.f,a7=0.f;
    for (int k = 0; k < md; k += 8) {
        int2 e[8];
        uint4 r[8];
        #pragma unroll
        for (int c = 0; c < 8; ++c) {
            int idx = (k + c < deg) ? start + k + c : lastIdx;
            long long w = __builtin_nontemporal_load(&epq[idx]);  // stream: keep out of L2
            e[c].x = (int)(w & 0xffffffffll);
            e[c].y = (int)(w >> 32);
            if (k + c >= deg) e[c].y = 0;
        }
        #pragma unroll
        for (int c = 0; c < 8; ++c)
            r[c] = other[(size_t)e[c].x * 8 + q];                 // reused: normal caching
        #pragma unroll
        for (int c = 0; c < 8; ++c) {
            float v = __int_as_float(e[c].y);
            a0 = fmaf(v, bf_lo(r[c].x), a0);  a1 = fmaf(v, bf_hi(r[c].x), a1);
            a2 = fmaf(v, bf_lo(r[c].y), a2);  a3 = fmaf(v, bf_hi(r[c].y), a3);
            a4 = fmaf(v, bf_lo(r[c].z), a4);  a5 = fmaf(v, bf_hi(r[c].z), a5);
            a6 = fmaf(v, bf_lo(r[c].w), a6);  a7 = fmaf(v, bf_hi(r[c].w), a7);
        }
    }

    if (!valid) return;
    uint4v o;
    o.x = (uint)f2bf(a0) | ((uint)f2bf(a1) << 16);
    o.y = (uint)f2bf(a2) | ((uint)f2bf(a3) << 16);
    o.z = (uint)f2bf(a4) | ((uint)f2bf(a5) << 16);
    o.w = (uint)f2bf(a6) | ((uint)f2bf(a7) << 16);
    __builtin_nontemporal_store(o, &((uint4v*)Enext)[(size_t)node * 8 + q]);
}

// ---------------------------------------------------------------------------
// Predict: sum 4 generations of bf16 rows, dot, /16; reg-loss block partials.
// ---------------------------------------------------------------------------
__global__ void predict_kernel(const int* __restrict__ user, const int* __restrict__ item_i,
                               const int* __restrict__ item_j,
                               const ushort* __restrict__ E0, const ushort* __restrict__ E1,
                               const ushort* __restrict__ E2, const ushort* __restrict__ E3,
                               const float* __restrict__ eu0, const float* __restrict__ ei0,
                               float* __restrict__ out, float* __restrict__ rbuf) {
    __shared__ float rpart[4];
    int t = blockIdx.x * blockDim.x + threadIdx.x;
    int b = t >> 6;
    int d = t & 63;
    int wv = threadIdx.x >> 6;
    float pi = 0.f, pj = 0.f, r = 0.f;
    if (b < BATCH) {
        size_t ru = (size_t)user[b] * EMBED + d;
        size_t ri = ((size_t)N_USERS + item_i[b]) * EMBED + d;
        size_t rj = ((size_t)N_USERS + item_j[b]) * EMBED + d;
        float ue = bfs(E0[ru]) + bfs(E1[ru]) + bfs(E2[ru]) + bfs(E3[ru]);
        float ie = bfs(E0[ri]) + bfs(E1[ri]) + bfs(E2[ri]) + bfs(E3[ri]);
        float je = bfs(E0[rj]) + bfs(E1[rj]) + bfs(E2[rj]) + bfs(E3[rj]);
        pi = ue * ie;
        pj = ue * je;
        float u0 = eu0[(size_t)user[b] * EMBED + d];
        float i0 = ei0[(size_t)item_i[b] * EMBED + d];
        float j0 = ei0[(size_t)item_j[b] * EMBED + d];
        r = u0 * u0 + i0 * i0 + j0 * j0;
    }
    #pragma unroll
    for (int off = 32; off > 0; off >>= 1) {
        pi += __shfl_down(pi, off);
        pj += __shfl_down(pj, off);
        r  += __shfl_down(r,  off);
    }
    if (d == 0 && b < BATCH) {
        out[b]         = pi * (1.0f / 16.0f);
        out[BATCH + b] = pj * (1.0f / 16.0f);
        rpart[wv] = r;
    }
    __syncthreads();
    if (threadIdx.x == 0)
        rbuf[blockIdx.x] = rpart[0] + rpart[1] + rpart[2] + rpart[3];
}

__global__ void finalize_reg(const float* __restrict__ rbuf, float* __restrict__ out) {
    __shared__ float lds[4];
    int tid = threadIdx.x;
    float s = 0.f;
    for (int i = tid; i < PRED_BLOCKS; i += 256) s += rbuf[i];
    #pragma unroll
    for (int off = 32; off > 0; off >>= 1) s += __shfl_down(s, off);
    if ((tid & 63) == 0) lds[tid >> 6] = s;
    __syncthreads();
    if (tid == 0)
        out[2 * BATCH] = (lds[0] + lds[1] + lds[2] + lds[3]) * (0.5f / (float)BATCH);
}

// ---------------------------------------------------------------------------
extern "C" void kernel_launch(void* const* d_in, const int* in_sizes, int n_in,
                              void* d_out, int out_size, void* d_ws, size_t ws_size,
                              hipStream_t stream) {
    const int*   user      = (const int*)  d_in[0];
    const int*   item_i    = (const int*)  d_in[1];
    const int*   item_j    = (const int*)  d_in[2];
    const int*   edge_src  = (const int*)  d_in[5];
    const int*   edge_dst  = (const int*)  d_in[6];
    const float* edge_vals = (const float*)d_in[7];
    const float* eu0       = (const float*)d_in[8];
    const float* ei0       = (const float*)d_in[9];
    const int    nnz       = in_sizes[5];

    float* out = (float*)d_out;

    // ---- workspace (~100 MB) ----
    ushort* E0   = (ushort*)d_ws;                // 19.2 MB each
    ushort* E1   = E0 + NE;
    ushort* E2   = E1 + NE;
    ushort* E3   = E2 + NE;
    int2*   ep   = (int2*)(E3 + NE);             // 19.2 MB sorted {dst,val}
    int*    offs = (int*)(ep + nnz);             // NNODES+2
    int*    Hbb  = offs + NNODES + 2;            // 586*512 = 300,032
    int*    bsum = Hbb + HBB_N;                  // SNB (147)
    int*    perm = bsum + 256;                   // NNODES
    float*  rbuf = (float*)(perm + NNODES);      // PRED_BLOCKS
    int2*   ebuf = (int2*)E1;                    // alias: dead before gathers

    const int initBlocks = (int)((NE / 4 + 1023) / 1024);   // 2344

    // 1) fused init(E0) + bucket histogram (no global atomics)
    init_and_hist<<<PBLK + initBlocks, 1024, 0, stream>>>(
        eu0, ei0, E0, edge_src, Hbb, nnz);
    // 2-3) scan Hbb
    scan_local<<<SNB, 256, 0, stream>>>(Hbb, bsum, HBB_N);
    scan_add2<<<SNB, 1024, 0, stream>>>(Hbb, bsum, HBB_N, SNB);
    // 4) single-pass LDS partition into bucket runs
    partition2<<<PBLK, 1024, 0, stream>>>(edge_src, edge_dst, edge_vals,
                                          Hbb, ebuf, nnz);
    // 5) node sort + offs + contiguous ep + ascending perm
    bucket_sort_perm<<<NBUCK, 1024, 0, stream>>>(Hbb, ebuf, offs, ep, perm, nnz);
    // 6-8) propagation layers (nontemporal ep/Enext streams)
    const int gblocks = (int)((((NNODES + 7) / 8) * 64 + 255) / 256);
    gather_E<<<gblocks, 256, 0, stream>>>(offs, ep, perm, E0, E1, nnz);
    gather_E<<<gblocks, 256, 0, stream>>>(offs, ep, perm, E1, E2, nnz);
    gather_E<<<gblocks, 256, 0, stream>>>(offs, ep, perm, E2, E3, nnz);
    // 9-10) predictions + reg loss
    predict_kernel<<<PRED_BLOCKS, 256, 0, stream>>>(
        user, item_i, item_j, E0, E1, E2, E3, eu0, ei0, out, rbuf);
    finalize_reg<<<1, 256, 0, stream>>>(rbuf, out);
}

// Round 20
// 312.056 us; speedup vs baseline: 1.2448x; 1.2448x over previous
//
#include <hip/hip_runtime.h>

#define N_USERS 100000
#define M_ITEMS 50000
#define NNODES  (N_USERS + M_ITEMS)
#define EMBED   64
#define BATCH   8192

#define NU_E ((size_t)N_USERS * EMBED)
#define NE   ((size_t)NNODES * EMBED)    // 9,600,000 elements

#define NPB    256                        // nodes per CSR bucket
#define NBUCK  ((NNODES + NPB - 1) / NPB) // 586
#define PBLK   512                        // partition blocks (1 LDS pass each)
#define PTILE  4688                       // edges per block (512*4688 >= nnz)
#define HBB_N  (NBUCK * PBLK)             // 300,032
#define SCHUNK 2048                       // scan elems per block (256 thr x 8)
#define SNB    ((HBB_N + SCHUNK - 1) / SCHUNK) // 147
#define BCAP   6784                       // LDS capacity per bucket sort
#define PRED_BLOCKS ((BATCH * 64) / 256)  // 2048

typedef unsigned int uint;

static __device__ __forceinline__ ushort f2bf(float f) {
    uint u = __float_as_uint(f);
    return (ushort)((u + 0x7fffu + ((u >> 16) & 1u)) >> 16);
}
static __device__ __forceinline__ float bf_lo(uint u) { return __uint_as_float(u << 16); }
static __device__ __forceinline__ float bf_hi(uint u) { return __uint_as_float(u & 0xffff0000u); }
static __device__ __forceinline__ float bfs(ushort u) { return __uint_as_float((uint)u << 16); }

// ---------------------------------------------------------------------------
// Fused: blocks [0,PBLK)  = per-block bucket hist -> Hbb[bucket*PBLK+blk]
//        blocks [PBLK,..) = E0 = bf16(concat(eu0, ei0)).
// ---------------------------------------------------------------------------
__global__ void init_and_hist(const float* __restrict__ eu, const float* __restrict__ ei,
                              ushort* __restrict__ E0,
                              const int* __restrict__ src, int* __restrict__ Hbb,
                              int nnz) {
    __shared__ int h[NBUCK];
    if (blockIdx.x < PBLK) {
        for (int i = threadIdx.x; i < NBUCK; i += 1024) h[i] = 0;
        __syncthreads();
        int base = blockIdx.x * PTILE;
        int end  = min(base + PTILE, nnz);
        for (int i = base + threadIdx.x; i < end; i += 1024)
            atomicAdd(&h[src[i] >> 8], 1);
        __syncthreads();
        for (int i = threadIdx.x; i < NBUCK; i += 1024)
            Hbb[i * PBLK + blockIdx.x] = h[i];
    } else {
        size_t t = (size_t)(blockIdx.x - PBLK) * 1024 + threadIdx.x;
        const size_t nu4 = NU_E / 4;
        const size_t n4  = NE / 4;
        if (t >= n4) return;
        float4 v = (t < nu4) ? ((const float4*)eu)[t] : ((const float4*)ei)[t - nu4];
        ((ushort4*)E0)[t] = make_ushort4(f2bf(v.x), f2bf(v.y), f2bf(v.z), f2bf(v.w));
    }
}

// ---------------------------------------------------------------------------
// Scan phase A: block-local exclusive scan of 2048 elems (256 thr x 8)
// ---------------------------------------------------------------------------
__global__ void scan_local(int* __restrict__ h, int* __restrict__ bsum, int n) {
    __shared__ int lds[256];
    const int tid = threadIdx.x;
    const int base = blockIdx.x * SCHUNK + tid * 8;
    int v[8]; int s = 0;
    #pragma unroll
    for (int c = 0; c < 8; ++c) { v[c] = (base + c < n) ? h[base + c] : 0; s += v[c]; }
    lds[tid] = s;
    __syncthreads();
    for (int off = 1; off < 256; off <<= 1) {
        int t = (tid >= off) ? lds[tid - off] : 0;
        __syncthreads();
        lds[tid] += t;
        __syncthreads();
    }
    if (tid == 255) bsum[blockIdx.x] = lds[255];
    int run = (tid > 0) ? lds[tid - 1] : 0;
    #pragma unroll
    for (int c = 0; c < 8; ++c) {
        int t = v[c];
        if (base + c < n) h[base + c] = run;
        run += t;
    }
}

// ---------------------------------------------------------------------------
// Scan phase B+C fused: re-scan bsum in LDS, add block prefix.
// ---------------------------------------------------------------------------
__global__ void scan_add2(int* __restrict__ h, const int* __restrict__ bsum,
                          int n, int nblk) {
    __shared__ int lds[256];
    int tid = threadIdx.x;
    if (tid < 256) lds[tid] = (tid < nblk) ? bsum[tid] : 0;
    __syncthreads();
    for (int off = 1; off < 256; off <<= 1) {
        int t = (tid >= off && tid < 256) ? lds[tid - off] : 0;
        __syncthreads();
        if (tid < 256) lds[tid] += t;
        __syncthreads();
    }
    int prefix = (blockIdx.x > 0) ? lds[blockIdx.x - 1] : 0;
    int lim = min(blockIdx.x * SCHUNK + SCHUNK, n);
    for (int i = blockIdx.x * SCHUNK + tid; i < lim; i += 1024)
        h[i] += prefix;
}

// ---------------------------------------------------------------------------
// Partition: single LDS pass per block (PTILE edges), counting sort in LDS,
// contiguous run write-out using Hbb global cursors.
// ebuf.x = (src & 255) | (dst_local << 8)
// ---------------------------------------------------------------------------
__global__ void __launch_bounds__(1024)
partition2(const int* __restrict__ src, const int* __restrict__ dst,
           const float* __restrict__ vals, const int* __restrict__ Hbb,
           int2* __restrict__ ebuf, int nnz) {
    __shared__ int2 data[PTILE];      // 37.5 KB
    __shared__ int  cnt[NBUCK];
    __shared__ int  cur[NBUCK];
    __shared__ int  s[1024];
    const int blk = blockIdx.x;
    const int tid = threadIdx.x;
    const int base = blk * PTILE;
    const int end  = min(base + PTILE, nnz);

    for (int i = tid; i < NBUCK; i += 1024) cnt[i] = 0;
    __syncthreads();
    for (int i = base + tid; i < end; i += 1024)
        atomicAdd(&cnt[src[i] >> 8], 1);
    __syncthreads();
    s[tid] = (tid < NBUCK) ? cnt[tid] : 0;
    __syncthreads();
    for (int off = 1; off < 1024; off <<= 1) {
        int t = (tid >= off) ? s[tid - off] : 0;
        __syncthreads();
        s[tid] += t;
        __syncthreads();
    }
    if (tid < NBUCK) cur[tid] = (tid > 0) ? s[tid - 1] : 0;
    __syncthreads();
    for (int i = base + tid; i < end; i += 1024) {
        int sv = src[i];
        int d  = dst[i];
        float v = vals[i];
        if (d >= N_USERS) d -= N_USERS;          // bipartite-local dst index
        int p = atomicAdd(&cur[sv >> 8], 1);
        data[p] = make_int2((sv & 255) | (d << 8), __float_as_int(v));
    }
    __syncthreads();
    int grp = tid >> 4, lane16 = tid & 15;        // 64 groups of 16
    for (int b = grp; b < NBUCK; b += 64) {
        int lbeg = (b > 0) ? s[b - 1] : 0;
        int c  = cnt[b];
        int gb = Hbb[b * PBLK + blk];
        for (int j = lane16; j < c; j += 16)
            ebuf[gb + j] = data[lbeg + j];
    }
}

// ---------------------------------------------------------------------------
// One block per bucket: LDS node counts + scan -> offs[], LDS-staged node
// sort -> fully contiguous ep write, + ascending-degree perm.
// ---------------------------------------------------------------------------
__global__ void __launch_bounds__(1024)
bucket_sort_perm(const int* __restrict__ Hbb, const int2* __restrict__ ebuf,
                 int* __restrict__ offs, int2* __restrict__ ep,
                 int* __restrict__ perm, int nnz) {
    __shared__ int2 data[BCAP];       // 54.3 KB
    __shared__ int cnt[256], sc[256], cur[256], dsc[256];
    int b   = blockIdx.x;
    int tid = threadIdx.x;
    int beg = Hbb[b * PBLK];
    int end = (b + 1 < NBUCK) ? Hbb[(b + 1) * PBLK] : nnz;
    int blen = end - beg;
    if (tid < 256) cnt[tid] = 0;
    __syncthreads();
    for (int i = beg + tid; i < end; i += 1024)
        atomicAdd(&cnt[ebuf[i].x & 255], 1);
    __syncthreads();
    if (tid < 256) sc[tid] = cnt[tid];
    __syncthreads();
    for (int off = 1; off < 256; off <<= 1) {
        int t = (tid >= off && tid < 256) ? sc[tid - off] : 0;
        __syncthreads();
        if (tid < 256) sc[tid] += t;
        __syncthreads();
    }
    if (tid < 256) {
        int lbase = (tid > 0) ? sc[tid - 1] : 0;
        int node = b * NPB + tid;
        if (node < NNODES) offs[node] = beg + lbase;
        cur[tid] = lbase;                          // local cursor
    }
    __syncthreads();
    if (blen <= BCAP) {
        for (int i = beg + tid; i < end; i += 1024) {
            int2 e = ebuf[i];
            int p = atomicAdd(&cur[e.x & 255], 1);
            data[p] = make_int2(e.x >> 8, e.y);
        }
        __syncthreads();
        for (int i = tid; i < blen; i += 1024)
            ep[beg + i] = data[i];
    } else {
        for (int i = beg + tid; i < end; i += 1024) {
            int2 e = ebuf[i];
            int p = atomicAdd(&cur[e.x & 255], 1);
            ep[beg + p] = make_int2(e.x >> 8, e.y);
        }
    }
    // ---- perm: counting sort by ASCENDING degree ----
    __syncthreads();
    if (tid < 256) sc[tid] = 0;
    __syncthreads();
    int nodeCount = min(NNODES - b * NPB, NPB);
    int bin = 0;
    if (tid < nodeCount) {
        bin = min(cnt[tid], 255);
        atomicAdd(&sc[bin], 1);
    }
    __syncthreads();
    if (tid < 256) dsc[tid] = sc[tid];
    __syncthreads();
    for (int off = 1; off < 256; off <<= 1) {
        int t = (tid >= off && tid < 256) ? dsc[tid - off] : 0;
        __syncthreads();
        if (tid < 256) dsc[tid] += t;
        __syncthreads();
    }
    if (tid < 256) cur[tid] = b * NPB + ((tid > 0) ? dsc[tid - 1] : 0);
    __syncthreads();
    if (tid < nodeCount) {
        int rank = atomicAdd(&cur[bin], 1);
        perm[rank] = b * NPB + tid;
    }
    if (b == 0 && tid == 0) offs[NNODES] = nnz;
}

// ---------------------------------------------------------------------------
// Gather layer (proven body): Enext[node] = sum val * Eprev[dst]
// 8 nodes/wave (degree-sorted), 8 lanes/node, branch-free unroll-8.
// ---------------------------------------------------------------------------
__global__ void gather_E(const int* __restrict__ offs, const int2* __restrict__ ep,
                         const int* __restrict__ perm,
                         const ushort* __restrict__ Eprev, ushort* __restrict__ Enext,
                         int nnz) {
    int t = blockIdx.x * blockDim.x + threadIdx.x;
    int wave = t >> 6;
    int lane = t & 63;
    int g = lane >> 3;
    int q = lane & 7;
    int ln = wave * 8 + g;
    bool valid = ln < NNODES;
    int node = valid ? perm[ln] : 0;
    int start = valid ? offs[node] : 0;
    int deg   = valid ? offs[node + 1] - start : 0;
    bool isUser = node < N_USERS;
    const uint4* other = (const uint4*)(Eprev + (isUser ? NU_E : 0));
    int lastIdx = min(max(start + deg - 1, 0), nnz - 1);

    int md = deg;
    #pragma unroll
    for (int off = 8; off <= 32; off <<= 1) md = max(md, __shfl_xor(md, off));

    float a0=0.f,a1=0.f,a2=0.f,a3=0.f,a4=0.f,a5=0.f,a6=0.f,a7=0.f;
    for (int k = 0; k < md; k += 8) {
        int2 e[8];
        uint4 r[8];
        #pragma unroll
        for (int c = 0; c < 8; ++c) {
            int idx = (k + c < deg) ? start + k + c : lastIdx;
            e[c] = ep[idx];
            if (k + c >= deg) e[c].y = 0;
        }
        #pragma unroll
        for (int c = 0; c < 8; ++c)
            r[c] = other[(size_t)e[c].x * 8 + q];
        #pragma unroll
        for (int c = 0; c < 8; ++c) {
            float v = __int_as_float(e[c].y);
            a0 = fmaf(v, bf_lo(r[c].x), a0);  a1 = fmaf(v, bf_hi(r[c].x), a1);
            a2 = fmaf(v, bf_lo(r[c].y), a2);  a3 = fmaf(v, bf_hi(r[c].y), a3);
            a4 = fmaf(v, bf_lo(r[c].z), a4);  a5 = fmaf(v, bf_hi(r[c].z), a5);
            a6 = fmaf(v, bf_lo(r[c].w), a6);  a7 = fmaf(v, bf_hi(r[c].w), a7);
        }
    }

    if (!valid) return;
    uint4 o;
    o.x = (uint)f2bf(a0) | ((uint)f2bf(a1) << 16);
    o.y = (uint)f2bf(a2) | ((uint)f2bf(a3) << 16);
    o.z = (uint)f2bf(a4) | ((uint)f2bf(a5) << 16);
    o.w = (uint)f2bf(a6) | ((uint)f2bf(a7) << 16);
    ((uint4*)Enext)[(size_t)node * 8 + q] = o;
}

// ---------------------------------------------------------------------------
// Predict: sum 4 generations of bf16 rows, dot, /16; reg-loss block partials.
// ---------------------------------------------------------------------------
__global__ void predict_kernel(const int* __restrict__ user, const int* __restrict__ item_i,
                               const int* __restrict__ item_j,
                               const ushort* __restrict__ E0, const ushort* __restrict__ E1,
                               const ushort* __restrict__ E2, const ushort* __restrict__ E3,
                               const float* __restrict__ eu0, const float* __restrict__ ei0,
                               float* __restrict__ out, float* __restrict__ rbuf) {
    __shared__ float rpart[4];
    int t = blockIdx.x * blockDim.x + threadIdx.x;
    int b = t >> 6;
    int d = t & 63;
    int wv = threadIdx.x >> 6;
    float pi = 0.f, pj = 0.f, r = 0.f;
    if (b < BATCH) {
        size_t ru = (size_t)user[b] * EMBED + d;
        size_t ri = ((size_t)N_USERS + item_i[b]) * EMBED + d;
        size_t rj = ((size_t)N_USERS + item_j[b]) * EMBED + d;
        float ue = bfs(E0[ru]) + bfs(E1[ru]) + bfs(E2[ru]) + bfs(E3[ru]);
        float ie = bfs(E0[ri]) + bfs(E1[ri]) + bfs(E2[ri]) + bfs(E3[ri]);
        float je = bfs(E0[rj]) + bfs(E1[rj]) + bfs(E2[rj]) + bfs(E3[rj]);
        pi = ue * ie;
        pj = ue * je;
        float u0 = eu0[(size_t)user[b] * EMBED + d];
        float i0 = ei0[(size_t)item_i[b] * EMBED + d];
        float j0 = ei0[(size_t)item_j[b] * EMBED + d];
        r = u0 * u0 + i0 * i0 + j0 * j0;
    }
    #pragma unroll
    for (int off = 32; off > 0; off >>= 1) {
        pi += __shfl_down(pi, off);
        pj += __shfl_down(pj, off);
        r  += __shfl_down(r,  off);
    }
    if (d == 0 && b < BATCH) {
        out[b]         = pi * (1.0f / 16.0f);
        out[BATCH + b] = pj * (1.0f / 16.0f);
        rpart[wv] = r;
    }
    __syncthreads();
    if (threadIdx.x == 0)
        rbuf[blockIdx.x] = rpart[0] + rpart[1] + rpart[2] + rpart[3];
}

__global__ void finalize_reg(const float* __restrict__ rbuf, float* __restrict__ out) {
    __shared__ float lds[4];
    int tid = threadIdx.x;
    float s = 0.f;
    for (int i = tid; i < PRED_BLOCKS; i += 256) s += rbuf[i];
    #pragma unroll
    for (int off = 32; off > 0; off >>= 1) s += __shfl_down(s, off);
    if ((tid & 63) == 0) lds[tid >> 6] = s;
    __syncthreads();
    if (tid == 0)
        out[2 * BATCH] = (lds[0] + lds[1] + lds[2] + lds[3]) * (0.5f / (float)BATCH);
}

// ---------------------------------------------------------------------------
extern "C" void kernel_launch(void* const* d_in, const int* in_sizes, int n_in,
                              void* d_out, int out_size, void* d_ws, size_t ws_size,
                              hipStream_t stream) {
    const int*   user      = (const int*)  d_in[0];
    const int*   item_i    = (const int*)  d_in[1];
    const int*   item_j    = (const int*)  d_in[2];
    const int*   edge_src  = (const int*)  d_in[5];
    const int*   edge_dst  = (const int*)  d_in[6];
    const float* edge_vals = (const float*)d_in[7];
    const float* eu0       = (const float*)d_in[8];
    const float* ei0       = (const float*)d_in[9];
    const int    nnz       = in_sizes[5];

    float* out = (float*)d_out;

    // ---- workspace (~100 MB) ----
    ushort* E0   = (ushort*)d_ws;                // 19.2 MB each
    ushort* E1   = E0 + NE;
    ushort* E2   = E1 + NE;
    ushort* E3   = E2 + NE;
    int2*   ep   = (int2*)(E3 + NE);             // 19.2 MB sorted {dst,val}
    int*    offs = (int*)(ep + nnz);             // NNODES+2
    int*    Hbb  = offs + NNODES + 2;            // 586*512 = 300,032
    int*    bsum = Hbb + HBB_N;                  // SNB (147)
    int*    perm = bsum + 256;                   // NNODES
    float*  rbuf = (float*)(perm + NNODES);      // PRED_BLOCKS
    int2*   ebuf = (int2*)E1;                    // alias: dead before gathers

    const int initBlocks = (int)((NE / 4 + 1023) / 1024);   // 2344

    // 1) fused init(E0) + bucket histogram (no global atomics)
    init_and_hist<<<PBLK + initBlocks, 1024, 0, stream>>>(
        eu0, ei0, E0, edge_src, Hbb, nnz);
    // 2-3) scan Hbb
    scan_local<<<SNB, 256, 0, stream>>>(Hbb, bsum, HBB_N);
    scan_add2<<<SNB, 1024, 0, stream>>>(Hbb, bsum, HBB_N, SNB);
    // 4) single-pass LDS partition into bucket runs
    partition2<<<PBLK, 1024, 0, stream>>>(edge_src, edge_dst, edge_vals,
                                          Hbb, ebuf, nnz);
    // 5) node sort + offs + contiguous ep + ascending perm
    bucket_sort_perm<<<NBUCK, 1024, 0, stream>>>(Hbb, ebuf, offs, ep, perm, nnz);
    // 6-8) propagation layers
    const int gblocks = (int)((((NNODES + 7) / 8) * 64 + 255) / 256);
    gather_E<<<gblocks, 256, 0, stream>>>(offs, ep, perm, E0, E1, nnz);
    gather_E<<<gblocks, 256, 0, stream>>>(offs, ep, perm, E1, E2, nnz);
    gather_E<<<gblocks, 256, 0, stream>>>(offs, ep, perm, E2, E3, nnz);
    // 9-10) predictions + reg loss
    predict_kernel<<<PRED_BLOCKS, 256, 0, stream>>>(
        user, item_i, item_j, E0, E1, E2, E3, eu0, ei0, out, rbuf);
    finalize_reg<<<1, 256, 0, stream>>>(rbuf, out);
}